// Round 8
// baseline (327.774 us; speedup 1.0000x reference)
//
#include <hip/hip_runtime.h>
#include <hip/hip_bf16.h>
#include <cstdint>
#include <cstddef>

#define B_  8
#define N_  1024
#define D_  768
#define H_  12
#define DH_ 64
#define M_  (B_*N_)     // 8192 rows of X
#define D3_ (3*D_)      // 2304

typedef __bf16 bf16;
typedef __bf16 bf16x4 __attribute__((ext_vector_type(4)));
typedef __bf16 bf16x8 __attribute__((ext_vector_type(8)));
typedef float  floatx4 __attribute__((ext_vector_type(4)));

// async global->LDS, 16B/lane; LDS dest = wave-uniform base + lane*16 (m97/m104)
__device__ __forceinline__ void async16(const void* g, void* l) {
  __builtin_amdgcn_global_load_lds(
      (const __attribute__((address_space(1))) unsigned int*)g,
      (__attribute__((address_space(3))) unsigned int*)l, 16, 0, 0);
}

// ------------- detect dtype (bf16 vs fp32) + ingest small tensors ------------
__global__ __launch_bounds__(256) void detect_small_k(
    const unsigned int* __restrict__ xraw, const void* bq, const void* bp,
    const void* gm, int* __restrict__ flag, bf16* bqd, bf16* bpd, float* gmd) {
  __shared__ int sc;
  if (threadIdx.x == 0) sc = 0;
  __syncthreads();
  int cnt = 0;
  for (int j = 0; j < 8; j++) {
    unsigned int w = xraw[threadIdx.x * 8 + j];
    unsigned int e = (w >> 7) & 0xFF;
    cnt += (e >= 100 && e <= 140) ? 1 : 0;
  }
  atomicAdd(&sc, cnt);
  __syncthreads();
  int f = (sc > 1024) ? 1 : 0;   // bf16 if low-u16 exponents look normal
  if (threadIdx.x == 0) *flag = f;
  for (int i = threadIdx.x; i < D3_; i += 256)
    bqd[i] = f ? ((const bf16*)bq)[i] : (bf16)((const float*)bq)[i];
  for (int i = threadIdx.x; i < D_; i += 256)
    bpd[i] = f ? ((const bf16*)bp)[i] : (bf16)((const float*)bp)[i];
  if (threadIdx.x < B_)
    gmd[threadIdx.x] = f ? (float)((const bf16*)gm)[threadIdx.x]
                         : ((const float*)gm)[threadIdx.x];
}

// ---------- bulk ingest, x + dist in one launch (vectorized x4) --------------
__device__ __forceinline__ void ingest_span(const void* src, bf16* dst, int f,
                                            long n4, long i0, long stride) {
  if (f) {
    const ushort2* s = (const ushort2*)src;
    ushort2* d = (ushort2*)dst;
    for (long i = i0; i < n4 * 2; i += stride) d[i] = s[i];
  } else {
    const float4* s = (const float4*)src;
    for (long i = i0; i < n4; i += stride) {
      float4 v = s[i];
      bf16x4 o = { (bf16)v.x, (bf16)v.y, (bf16)v.z, (bf16)v.w };
      *(bf16x4*)(dst + i * 4) = o;
    }
  }
}
#define XBLOCKS 1024
#define DBLOCKS 256
__global__ __launch_bounds__(256) void ingest2_k(const void* __restrict__ x,
                                                 bf16* __restrict__ xb,
                                                 const void* __restrict__ dist,
                                                 bf16* __restrict__ distb,
                                                 const int* __restrict__ flag) {
  int f = *flag;
  if (blockIdx.x < XBLOCKS) {
    long i0 = (long)blockIdx.x * 256 + threadIdx.x;
    ingest_span(x, xb, f, (long)M_ * D_ / 4, i0, (long)XBLOCKS * 256);
  } else {
    long i0 = (long)(blockIdx.x - XBLOCKS) * 256 + threadIdx.x;
    ingest_span(dist, distb, f, (long)N_ * N_ / 4, i0, (long)DBLOCKS * 256);
  }
}

// ------- tiled ingest+transpose of both weights: src[R][C] -> dst[C][R] ------
__global__ __launch_bounds__(256) void ingest_wt_k(const void* srcA, bf16* dstA,
                                                   const void* srcB, bf16* dstB,
                                                   const int* __restrict__ flag,
                                                   int tilesA, int tcA) {
  __shared__ bf16 t[64][72];
  int f = *flag;
  int bid = blockIdx.x;
  const void* src; bf16* dst; int C;
  int tc;
  if (bid < tilesA) { src = srcA; dst = dstA; C = D3_; tc = tcA; }
  else { bid -= tilesA; src = srcB; dst = dstB; C = D_; tc = D_ / 64; }
  int c0 = (bid % tc) * 64, r0 = (bid / tc) * 64;
  int i = threadIdx.x >> 2, j0 = (threadIdx.x & 3) * 16;
  if (f) {
    const bf16* s = (const bf16*)src + (size_t)(r0 + i) * C + c0 + j0;
#pragma unroll
    for (int jj = 0; jj < 16; jj += 8) *(bf16x8*)&t[i][j0 + jj] = *(const bf16x8*)(s + jj);
  } else {
    const float4* s = (const float4*)((const float*)src + (size_t)(r0 + i) * C + c0 + j0);
#pragma unroll
    for (int jj = 0; jj < 4; jj++) {
      float4 v = s[jj];
      bf16x4 o = { (bf16)v.x, (bf16)v.y, (bf16)v.z, (bf16)v.w };
      *(bf16x4*)&t[i][j0 + jj * 4] = o;
    }
  }
  __syncthreads();
  bf16* d = dst + (size_t)(c0 + i) * D_ + r0 + j0;   // R = D_ always
#pragma unroll
  for (int jj = 0; jj < 16; jj++) d[jj] = t[j0 + jj][i];
}

// ---------------- wave-private GEMM: C = A[M][K] * Bt[N][K]^T + bias ---------
// NO barriers in the K-loop: each wave owns a private LDS slab (A: AMI*16 rows,
// B: 64 rows, x32 k). Stage via global_load_lds -> wave-scoped s_waitcnt
// vmcnt(0) -> ds_read own frags -> MFMA. Waves drift freely; latency hidden by
// SIMD-mates' MFMA (m114). WAR on slab safe: a wave's ds_reads execute before
// its dependent MFMAs issue, which precede the next stage's issue.
// AMI = m-frags per wave (4 -> wave 64x64, 2 -> wave 32x64). Block = 2x2 waves.
// MODE 0: QKV epilogue -> Q[b][h][n][d], K[b][h][n][d], Vt[b][h][d][n] (bf16)
// MODE 1: proj epilogue -> out[row][col]; fp32 when *flag==0, bf16 when 1
template <int MODE, int AMI>
__global__ __launch_bounds__(256) void gemm_bt(const bf16* __restrict__ A,
                                               const bf16* __restrict__ Bt,
                                               const bf16* __restrict__ bias,
                                               bf16* __restrict__ O0,
                                               bf16* __restrict__ O1,
                                               bf16* __restrict__ O2,
                                               float* __restrict__ OF,
                                               const int* __restrict__ flag,
                                               int Kdim) {
  constexpr int SLAB = (AMI + 4) * 1024;           // bytes per wave (A + B)
  int n0 = blockIdx.x * 128, m0 = blockIdx.y * (AMI * 32);
  int tid = threadIdx.x, wave = tid >> 6, lane = tid & 63;
  int wm = (wave >> 1) * (AMI * 16), wn = (wave & 1) * 64;
  int cl = lane & 15, qd = lane >> 4;
  __shared__ __align__(16) char slab[4 * SLAB];
  bf16* Aw = (bf16*)(slab + wave * SLAB);          // AMI chunks of 1024B
  bf16* Bw = Aw + AMI * 512;                        // 4 chunks of 1024B
  floatx4 acc[AMI][4] = {};

  int srow = lane >> 2, sko = (lane & 3) * 8;      // chunk: 16 rows x 32 k

  const bf16* Ab = A + (size_t)(m0 + wm + srow) * Kdim + sko;
  const bf16* Bb = Bt + (size_t)(n0 + wn + srow) * Kdim + sko;

  for (int kt = 0; kt < Kdim; kt += 32) {
#pragma unroll
    for (int i = 0; i < AMI; i++)
      async16(Ab + (size_t)(i * 16) * Kdim + kt, (char*)Aw + i * 1024);
#pragma unroll
    for (int i = 0; i < 4; i++)
      async16(Bb + (size_t)(i * 16) * Kdim + kt, (char*)Bw + i * 1024);
    asm volatile("s_waitcnt vmcnt(0)" ::: "memory");  // wave-scoped drain

    bf16x8 af[AMI], bfv[4];
#pragma unroll
    for (int mi = 0; mi < AMI; mi++)
      af[mi] = *(const bf16x8*)(Aw + (mi * 16 + cl) * 32 + qd * 8);
#pragma unroll
    for (int ni = 0; ni < 4; ni++)
      bfv[ni] = *(const bf16x8*)(Bw + (ni * 16 + cl) * 32 + qd * 8);
#pragma unroll
    for (int mi = 0; mi < AMI; mi++)
#pragma unroll
      for (int ni = 0; ni < 4; ni++)
        acc[mi][ni] = __builtin_amdgcn_mfma_f32_16x16x32_bf16(af[mi], bfv[ni],
                                                              acc[mi][ni], 0, 0, 0);
  }

  int fbf16 = (MODE == 1) ? *flag : 0;
#pragma unroll
  for (int ni = 0; ni < 4; ni++) {
    int colb = n0 + wn + ni * 16;
    float bv = (float)bias[colb + cl];
#pragma unroll
    for (int mi = 0; mi < AMI; mi++) {
#pragma unroll
      for (int r = 0; r < 4; r++) {
        int row = m0 + wm + mi * 16 + qd * 4 + r;
        float v = acc[mi][ni][r] + bv;
        if (MODE == 0) {
          int t = colb / D_;
          int rem = colb % D_;
          int h = rem >> 6;
          int d = (rem & 63) + cl;
          int b = row >> 10, n = row & 1023;
          size_t bh = (size_t)b * H_ + h;
          if (t == 0)      O0[(bh * N_ + n) * DH_ + d] = (bf16)v;
          else if (t == 1) O1[(bh * N_ + n) * DH_ + d] = (bf16)v;
          else             O2[(bh * DH_ + d) * N_ + n] = (bf16)v;
        } else {
          size_t oi = (size_t)row * D_ + colb + cl;
          if (fbf16) O0[oi] = (bf16)v;
          else       OF[oi] = v;
        }
      }
    }
  }
}

// ---------------- fused flash attention, S^T formulation (R6, unchanged) -----
#define KROW 72
#define VROW 136
#define PSTR 136
__global__ __launch_bounds__(256, 4) void attn_k(const bf16* __restrict__ Q,
                                                 const bf16* __restrict__ Kp,
                                                 const bf16* __restrict__ Vt,
                                                 const float* __restrict__ gammaf,
                                                 const bf16* __restrict__ dist,
                                                 bf16* __restrict__ O) {
  int bh = blockIdx.x % (B_ * H_);        // idx%8 == bh%8 -> same-bh same XCD
  int q0 = (blockIdx.x / (B_ * H_)) * 64;
  int b = bh / H_, h = bh % H_;
  int tid = threadIdx.x, wave = tid >> 6, lane = tid & 63;
  int cl = lane & 15, qd = lane >> 4;
  __shared__ __align__(16) bf16 Ks[128 * KROW];   // 18 KB (P slabs alias here)
  __shared__ __align__(16) bf16 Vs[64 * VROW];    // 17 KB

  bf16x8 aq[2];
  {
    const bf16* Qg = Q + ((size_t)bh * N_ + q0 + wave * 16 + cl) * DH_;
    aq[0] = *(const bf16x8*)(Qg + qd * 8);
    aq[1] = *(const bf16x8*)(Qg + 32 + qd * 8);
  }

  floatx4 oacc[4] = {};
  float lsum = 0.f;
  const float LOG2E = 1.4426950408889634f;
  const float SCL = 0.03608439182435161f * LOG2E;   // 768^-0.5 * log2(e)
  float gl = gammaf[b] * LOG2E;

  const bf16* Kg0 = Kp + (size_t)bh * N_ * DH_;
  const bf16* Vg0 = Vt + (size_t)bh * DH_ * N_;
  const bf16* Dg  = dist + (size_t)(q0 + wave * 16 + cl) * N_ + qd * 4;
  int krow = tid >> 1, kh = tid & 1;
  int vrow = tid >> 2, vq = tid & 3;
  bf16* pslab = Ks + wave * 2304;   // 16 rows x PSTR=136 = 2176 <= 2304

  for (int t0 = 0; t0 < N_; t0 += 128) {
    const bf16* Kg = Kg0 + (size_t)(t0 + krow) * DH_ + kh * 32;
    bf16x8 kv[4];
#pragma unroll
    for (int j = 0; j < 4; j++) kv[j] = *(const bf16x8*)(Kg + j * 8);
    const bf16* Vg = Vg0 + (size_t)vrow * N_ + t0 + vq * 8;
    bf16x8 vv[4];
#pragma unroll
    for (int p = 0; p < 4; p++) vv[p] = *(const bf16x8*)(Vg + p * 32);
    bf16x4 ddr[8];
#pragma unroll
    for (int ni = 0; ni < 8; ni++) ddr[ni] = *(const bf16x4*)(Dg + t0 + ni * 16);

    __syncthreads();
#pragma unroll
    for (int j = 0; j < 4; j++)
      *(bf16x8*)(Ks + krow * KROW + kh * 32 + j * 8) = kv[j];
#pragma unroll
    for (int p = 0; p < 4; p++)
      *(bf16x8*)(Vs + vrow * VROW + vq * 8 + p * 32) = vv[p];
    __syncthreads();

    floatx4 sacc[8] = {};
#pragma unroll
    for (int kk = 0; kk < 2; kk++) {
#pragma unroll
      for (int ni = 0; ni < 8; ni++) {
        bf16x8 ak = *(const bf16x8*)(Ks + (ni * 16 + cl) * KROW + kk * 32 + qd * 8);
        sacc[ni] = __builtin_amdgcn_mfma_f32_16x16x32_bf16(ak, aq[kk], sacc[ni], 0, 0, 0);
      }
    }

    bf16x4 pk[8];
#pragma unroll
    for (int ni = 0; ni < 8; ni++) {
#pragma unroll
      for (int r = 0; r < 4; r++) {
        float p = __builtin_exp2f(sacc[ni][r] * SCL - gl * (float)ddr[ni][r]);
        lsum += p;
        pk[ni][r] = (bf16)p;
      }
    }
    __syncthreads();   // all waves done reading Ks before P overwrites it

#pragma unroll
    for (int ni = 0; ni < 8; ni++)
      *(bf16x4*)(pslab + cl * PSTR + ni * 16 + qd * 4) = pk[ni];

#pragma unroll
    for (int kk = 0; kk < 4; kk++) {
      bf16x8 ap = *(const bf16x8*)(pslab + cl * PSTR + kk * 32 + qd * 8);
#pragma unroll
      for (int ni = 0; ni < 4; ni++) {
        bf16x8 bv = *(const bf16x8*)(Vs + (ni * 16 + cl) * VROW + kk * 32 + qd * 8);
        oacc[ni] = __builtin_amdgcn_mfma_f32_16x16x32_bf16(ap, bv, oacc[ni], 0, 0, 0);
      }
    }
  }

  lsum += __shfl_xor(lsum, 16, 64);
  lsum += __shfl_xor(lsum, 32, 64);

#pragma unroll
  for (int r = 0; r < 4; r++) {
    float inv = 1.f / __shfl(lsum, qd * 4 + r, 64);
    int qg = q0 + wave * 16 + qd * 4 + r;
    size_t base = ((size_t)(b * N_ + qg)) * D_ + h * DH_;
#pragma unroll
    for (int ni = 0; ni < 4; ni++)
      O[base + ni * 16 + cl] = (bf16)(oacc[ni][r] * inv);
  }
}

extern "C" void kernel_launch(void* const* d_in, const int* in_sizes, int n_in,
                              void* d_out, int out_size, void* d_ws, size_t ws_size,
                              hipStream_t stream) {
  const void* x     = d_in[0];
  const void* gamma = d_in[1];
  const void* dist  = d_in[2];
  const void* Wqkv  = d_in[3];
  const void* bqkv  = d_in[4];
  const void* Wproj = d_in[5];
  const void* bproj = d_in[6];

  char* ws = (char*)d_ws;
  size_t o = 0;
  int*   flag   = (int*)(ws + o);   o += 16;
  float* gammaf = (float*)(ws + o); o += 32;
  bf16*  xb     = (bf16*)(ws + o);  o += (size_t)M_ * D_ * 2;
  bf16*  distb  = (bf16*)(ws + o);  o += (size_t)N_ * N_ * 2;
  bf16*  bqkvb  = (bf16*)(ws + o);  o += (size_t)D3_ * 2;
  bf16*  bprojb = (bf16*)(ws + o);  o += (size_t)D_ * 2 + 8;
  bf16*  WqkvT  = (bf16*)(ws + o);  o += (size_t)D3_ * D_ * 2;
  bf16*  WprojT = (bf16*)(ws + o);  o += (size_t)D_ * D_ * 2;
  bf16*  Qp     = (bf16*)(ws + o);  o += (size_t)M_ * D_ * 2;
  bf16*  Kp     = (bf16*)(ws + o);  o += (size_t)M_ * D_ * 2;
  bf16*  Vtp    = (bf16*)(ws + o);  o += (size_t)M_ * D_ * 2;
  bf16*  Op     = (bf16*)(ws + o);  o += (size_t)M_ * D_ * 2;
  if (ws_size < o) return;

  detect_small_k<<<1, 256, 0, stream>>>((const unsigned int*)x, bqkv, bproj, gamma,
                                        flag, bqkvb, bprojb, gammaf);
  ingest2_k<<<XBLOCKS + DBLOCKS, 256, 0, stream>>>(x, xb, dist, distb, flag);
  int tilesA = (D3_ / 64) * (D_ / 64);          // 432
  int tilesB = (D_ / 64) * (D_ / 64);           // 144
  ingest_wt_k<<<tilesA + tilesB, 256, 0, stream>>>(Wqkv, WqkvT, Wproj, WprojT,
                                                   flag, tilesA, D3_ / 64);

  gemm_bt<0, 4><<<dim3(D3_ / 128, M_ / 128), 256, 0, stream>>>(
      xb, WqkvT, bqkvb, Qp, Kp, Vtp, nullptr, flag, D_);
  attn_k<<<dim3(B_ * H_ * (N_ / 64)), 256, 0, stream>>>(
      Qp, Kp, Vtp, gammaf, distb, Op);
  gemm_bt<1, 2><<<dim3(D_ / 128, M_ / 64), 256, 0, stream>>>(
      Op, WprojT, bprojb, (bf16*)d_out, nullptr, nullptr, (float*)d_out, flag, D_);
}

// Round 9
// 293.719 us; speedup vs baseline: 1.1159x; 1.1159x over previous
//
#include <hip/hip_runtime.h>
#include <hip/hip_bf16.h>
#include <cstdint>
#include <cstddef>

#define B_  8
#define N_  1024
#define D_  768
#define H_  12
#define DH_ 64
#define M_  (B_*N_)     // 8192 rows of X
#define D3_ (3*D_)      // 2304

typedef __bf16 bf16;
typedef __bf16 bf16x4 __attribute__((ext_vector_type(4)));
typedef __bf16 bf16x8 __attribute__((ext_vector_type(8)));
typedef float  floatx4 __attribute__((ext_vector_type(4)));

// async global->LDS, 16B/lane; LDS dest = wave-uniform base + lane*16 (m97/m104)
__device__ __forceinline__ void async16(const void* g, void* l) {
  __builtin_amdgcn_global_load_lds(
      (const __attribute__((address_space(1))) unsigned int*)g,
      (__attribute__((address_space(3))) unsigned int*)l, 16, 0, 0);
}

// ------------- detect dtype (bf16 vs fp32) + ingest small tensors ------------
__global__ __launch_bounds__(256) void detect_small_k(
    const unsigned int* __restrict__ xraw, const void* bq, const void* bp,
    const void* gm, int* __restrict__ flag, bf16* bqd, bf16* bpd, float* gmd) {
  __shared__ int sc;
  if (threadIdx.x == 0) sc = 0;
  __syncthreads();
  int cnt = 0;
  for (int j = 0; j < 8; j++) {
    unsigned int w = xraw[threadIdx.x * 8 + j];
    unsigned int e = (w >> 7) & 0xFF;
    cnt += (e >= 100 && e <= 140) ? 1 : 0;
  }
  atomicAdd(&sc, cnt);
  __syncthreads();
  int f = (sc > 1024) ? 1 : 0;   // bf16 if low-u16 exponents look normal
  if (threadIdx.x == 0) *flag = f;
  for (int i = threadIdx.x; i < D3_; i += 256)
    bqd[i] = f ? ((const bf16*)bq)[i] : (bf16)((const float*)bq)[i];
  for (int i = threadIdx.x; i < D_; i += 256)
    bpd[i] = f ? ((const bf16*)bp)[i] : (bf16)((const float*)bp)[i];
  if (threadIdx.x < B_)
    gmd[threadIdx.x] = f ? (float)((const bf16*)gm)[threadIdx.x]
                         : ((const float*)gm)[threadIdx.x];
}

// ---------- bulk ingest, x + dist in one launch (vectorized x4) --------------
__device__ __forceinline__ void ingest_span(const void* src, bf16* dst, int f,
                                            long n4, long i0, long stride) {
  if (f) {
    const ushort2* s = (const ushort2*)src;
    ushort2* d = (ushort2*)dst;
    for (long i = i0; i < n4 * 2; i += stride) d[i] = s[i];
  } else {
    const float4* s = (const float4*)src;
    for (long i = i0; i < n4; i += stride) {
      float4 v = s[i];
      bf16x4 o = { (bf16)v.x, (bf16)v.y, (bf16)v.z, (bf16)v.w };
      *(bf16x4*)(dst + i * 4) = o;
    }
  }
}
#define XBLOCKS 1024
#define DBLOCKS 256
__global__ __launch_bounds__(256) void ingest2_k(const void* __restrict__ x,
                                                 bf16* __restrict__ xb,
                                                 const void* __restrict__ dist,
                                                 bf16* __restrict__ distb,
                                                 const int* __restrict__ flag) {
  int f = *flag;
  if (blockIdx.x < XBLOCKS) {
    long i0 = (long)blockIdx.x * 256 + threadIdx.x;
    ingest_span(x, xb, f, (long)M_ * D_ / 4, i0, (long)XBLOCKS * 256);
  } else {
    long i0 = (long)(blockIdx.x - XBLOCKS) * 256 + threadIdx.x;
    ingest_span(dist, distb, f, (long)N_ * N_ / 4, i0, (long)DBLOCKS * 256);
  }
}

// ------- tiled ingest+transpose of both weights: src[R][C] -> dst[C][R] ------
__global__ __launch_bounds__(256) void ingest_wt_k(const void* srcA, bf16* dstA,
                                                   const void* srcB, bf16* dstB,
                                                   const int* __restrict__ flag,
                                                   int tilesA, int tcA) {
  __shared__ bf16 t[64][72];
  int f = *flag;
  int bid = blockIdx.x;
  const void* src; bf16* dst; int C;
  int tc;
  if (bid < tilesA) { src = srcA; dst = dstA; C = D3_; tc = tcA; }
  else { bid -= tilesA; src = srcB; dst = dstB; C = D_; tc = D_ / 64; }
  int c0 = (bid % tc) * 64, r0 = (bid / tc) * 64;
  int i = threadIdx.x >> 2, j0 = (threadIdx.x & 3) * 16;
  if (f) {
    const bf16* s = (const bf16*)src + (size_t)(r0 + i) * C + c0 + j0;
#pragma unroll
    for (int jj = 0; jj < 16; jj += 8) *(bf16x8*)&t[i][j0 + jj] = *(const bf16x8*)(s + jj);
  } else {
    const float4* s = (const float4*)((const float*)src + (size_t)(r0 + i) * C + c0 + j0);
#pragma unroll
    for (int jj = 0; jj < 4; jj++) {
      float4 v = s[jj];
      bf16x4 o = { (bf16)v.x, (bf16)v.y, (bf16)v.z, (bf16)v.w };
      *(bf16x4*)&t[i][j0 + jj * 4] = o;
    }
  }
  __syncthreads();
  bf16* d = dst + (size_t)(c0 + i) * D_ + r0 + j0;   // R = D_ always
#pragma unroll
  for (int jj = 0; jj < 16; jj++) d[jj] = t[j0 + jj][i];
}

// ---------------- GEMM: C = A[M][K] * Bt[N][K]^T + bias ----------------------
// R7 double-buffered K-loop + XCD-aware 1D-grid swizzle: xcd = id%8 owns a
// 1/8 by-slice (A-slab ~1.6 MB resident in its L2) and sweeps bx with the
// B-tile hot. BYL = gridY/8 (compile-time). NBX = grid x-extent (runtime).
// MODE 0: QKV epilogue -> Q[b][h][n][d], K[b][h][n][d], Vt[b][h][d][n] (bf16)
// MODE 1: proj epilogue -> out[row][col]; fp32 when *flag==0, bf16 when 1
template <int MODE, int TMI, int BYL>
__global__ __launch_bounds__(256) void gemm_bt(const bf16* __restrict__ A,
                                               const bf16* __restrict__ Bt,
                                               const bf16* __restrict__ bias,
                                               bf16* __restrict__ O0,
                                               bf16* __restrict__ O1,
                                               bf16* __restrict__ O2,
                                               float* __restrict__ OF,
                                               const int* __restrict__ flag,
                                               int Kdim) {
  constexpr int TM = TMI * 32;
  int id = blockIdx.x;
  int xcd = id & 7;
  int j = id >> 3;
  int bx = j / BYL;                       // n-tile (compile-time divisor)
  int by = xcd * BYL + (j % BYL);         // m-tile: same-XCD blocks share A-slab
  int n0 = bx * 128, m0 = by * TM;
  int tid = threadIdx.x, wave = tid >> 6, lane = tid & 63;
  int wm = (wave >> 1) * (TMI * 16), wn = (wave & 1) * 64;
  int cl = lane & 15, qd = lane >> 4;
  __shared__ __align__(16) bf16 As[2][TM * 32];
  __shared__ __align__(16) bf16 Bs[2][128 * 32];
  floatx4 acc[TMI][4] = {};

  int srow = lane >> 2, sko = (lane & 3) * 8;   // chunk = 16 rows x 32 k = 1024B

  auto stage = [&](int kt, int b) {
#pragma unroll
    for (int i = 0; i < TMI / 2; i++) {
      int c = wave * (TMI / 2) + i;
      int row = c * 16 + srow;
      async16(A + (size_t)(m0 + row) * Kdim + kt + sko, (char*)&As[b][0] + c * 1024);
    }
#pragma unroll
    for (int i = 0; i < 2; i++) {
      int c = wave * 2 + i;
      int row = c * 16 + srow;
      async16(Bt + (size_t)(n0 + row) * Kdim + kt + sko, (char*)&Bs[b][0] + c * 1024);
    }
  };
  auto compute = [&](int b) {
    bf16x8 af[TMI], bfv[4];
#pragma unroll
    for (int mi = 0; mi < TMI; mi++)
      af[mi] = *(const bf16x8*)(&As[b][0] + (wm + mi * 16 + cl) * 32 + qd * 8);
#pragma unroll
    for (int ni = 0; ni < 4; ni++)
      bfv[ni] = *(const bf16x8*)(&Bs[b][0] + (wn + ni * 16 + cl) * 32 + qd * 8);
#pragma unroll
    for (int mi = 0; mi < TMI; mi++)
#pragma unroll
      for (int ni = 0; ni < 4; ni++)
        acc[mi][ni] = __builtin_amdgcn_mfma_f32_16x16x32_bf16(af[mi], bfv[ni],
                                                              acc[mi][ni], 0, 0, 0);
  };

  stage(0, 0);
  for (int kt = 0; kt < Kdim; kt += 64) {
    __syncthreads();                        // buf0 loads drained; prev reads done
    if (kt + 32 < Kdim) stage(kt + 32, 1);  // in flight during compute(0)
    compute(0);
    __syncthreads();                        // buf1 loads drained; buf0 reads done
    if (kt + 64 < Kdim) stage(kt + 64, 0);
    if (kt + 32 < Kdim) compute(1);
  }

  int fbf16 = (MODE == 1) ? *flag : 0;
#pragma unroll
  for (int ni = 0; ni < 4; ni++) {
    int colb = n0 + wn + ni * 16;
    float bv = (float)bias[colb + cl];
#pragma unroll
    for (int mi = 0; mi < TMI; mi++) {
#pragma unroll
      for (int r = 0; r < 4; r++) {
        int row = m0 + wm + mi * 16 + qd * 4 + r;
        float v = acc[mi][ni][r] + bv;
        if (MODE == 0) {
          int t = colb / D_;
          int rem = colb % D_;
          int h = rem >> 6;
          int d = (rem & 63) + cl;
          int b = row >> 10, n = row & 1023;
          size_t bh = (size_t)b * H_ + h;
          if (t == 0)      O0[(bh * N_ + n) * DH_ + d] = (bf16)v;
          else if (t == 1) O1[(bh * N_ + n) * DH_ + d] = (bf16)v;
          else             O2[(bh * DH_ + d) * N_ + n] = (bf16)v;
        } else {
          size_t oi = (size_t)row * D_ + colb + cl;
          if (fbf16) O0[oi] = (bf16)v;
          else       OF[oi] = v;
        }
      }
    }
  }
}

// ---------------- fused flash attention, S^T formulation (R6, unchanged) -----
#define KROW 72
#define VROW 136
#define PSTR 136
__global__ __launch_bounds__(256, 4) void attn_k(const bf16* __restrict__ Q,
                                                 const bf16* __restrict__ Kp,
                                                 const bf16* __restrict__ Vt,
                                                 const float* __restrict__ gammaf,
                                                 const bf16* __restrict__ dist,
                                                 bf16* __restrict__ O) {
  int bh = blockIdx.x % (B_ * H_);        // idx%8 == bh%8 -> same-bh same XCD
  int q0 = (blockIdx.x / (B_ * H_)) * 64;
  int b = bh / H_, h = bh % H_;
  int tid = threadIdx.x, wave = tid >> 6, lane = tid & 63;
  int cl = lane & 15, qd = lane >> 4;
  __shared__ __align__(16) bf16 Ks[128 * KROW];   // 18 KB (P slabs alias here)
  __shared__ __align__(16) bf16 Vs[64 * VROW];    // 17 KB

  bf16x8 aq[2];
  {
    const bf16* Qg = Q + ((size_t)bh * N_ + q0 + wave * 16 + cl) * DH_;
    aq[0] = *(const bf16x8*)(Qg + qd * 8);
    aq[1] = *(const bf16x8*)(Qg + 32 + qd * 8);
  }

  floatx4 oacc[4] = {};
  float lsum = 0.f;
  const float LOG2E = 1.4426950408889634f;
  const float SCL = 0.03608439182435161f * LOG2E;   // 768^-0.5 * log2(e)
  float gl = gammaf[b] * LOG2E;

  const bf16* Kg0 = Kp + (size_t)bh * N_ * DH_;
  const bf16* Vg0 = Vt + (size_t)bh * DH_ * N_;
  const bf16* Dg  = dist + (size_t)(q0 + wave * 16 + cl) * N_ + qd * 4;
  int krow = tid >> 1, kh = tid & 1;
  int vrow = tid >> 2, vq = tid & 3;
  bf16* pslab = Ks + wave * 2304;   // 16 rows x PSTR=136 = 2176 <= 2304

  for (int t0 = 0; t0 < N_; t0 += 128) {
    const bf16* Kg = Kg0 + (size_t)(t0 + krow) * DH_ + kh * 32;
    bf16x8 kv[4];
#pragma unroll
    for (int j = 0; j < 4; j++) kv[j] = *(const bf16x8*)(Kg + j * 8);
    const bf16* Vg = Vg0 + (size_t)vrow * N_ + t0 + vq * 8;
    bf16x8 vv[4];
#pragma unroll
    for (int p = 0; p < 4; p++) vv[p] = *(const bf16x8*)(Vg + p * 32);
    bf16x4 ddr[8];
#pragma unroll
    for (int ni = 0; ni < 8; ni++) ddr[ni] = *(const bf16x4*)(Dg + t0 + ni * 16);

    __syncthreads();
#pragma unroll
    for (int j = 0; j < 4; j++)
      *(bf16x8*)(Ks + krow * KROW + kh * 32 + j * 8) = kv[j];
#pragma unroll
    for (int p = 0; p < 4; p++)
      *(bf16x8*)(Vs + vrow * VROW + vq * 8 + p * 32) = vv[p];
    __syncthreads();

    floatx4 sacc[8] = {};
#pragma unroll
    for (int kk = 0; kk < 2; kk++) {
#pragma unroll
      for (int ni = 0; ni < 8; ni++) {
        bf16x8 ak = *(const bf16x8*)(Ks + (ni * 16 + cl) * KROW + kk * 32 + qd * 8);
        sacc[ni] = __builtin_amdgcn_mfma_f32_16x16x32_bf16(ak, aq[kk], sacc[ni], 0, 0, 0);
      }
    }

    bf16x4 pk[8];
#pragma unroll
    for (int ni = 0; ni < 8; ni++) {
#pragma unroll
      for (int r = 0; r < 4; r++) {
        float p = __builtin_exp2f(sacc[ni][r] * SCL - gl * (float)ddr[ni][r]);
        lsum += p;
        pk[ni][r] = (bf16)p;
      }
    }
    __syncthreads();   // all waves done reading Ks before P overwrites it

#pragma unroll
    for (int ni = 0; ni < 8; ni++)
      *(bf16x4*)(pslab + cl * PSTR + ni * 16 + qd * 4) = pk[ni];

#pragma unroll
    for (int kk = 0; kk < 4; kk++) {
      bf16x8 ap = *(const bf16x8*)(pslab + cl * PSTR + kk * 32 + qd * 8);
#pragma unroll
      for (int ni = 0; ni < 4; ni++) {
        bf16x8 bv = *(const bf16x8*)(Vs + (ni * 16 + cl) * VROW + kk * 32 + qd * 8);
        oacc[ni] = __builtin_amdgcn_mfma_f32_16x16x32_bf16(ap, bv, oacc[ni], 0, 0, 0);
      }
    }
  }

  lsum += __shfl_xor(lsum, 16, 64);
  lsum += __shfl_xor(lsum, 32, 64);

#pragma unroll
  for (int r = 0; r < 4; r++) {
    float inv = 1.f / __shfl(lsum, qd * 4 + r, 64);
    int qg = q0 + wave * 16 + qd * 4 + r;
    size_t base = ((size_t)(b * N_ + qg)) * D_ + h * DH_;
#pragma unroll
    for (int ni = 0; ni < 4; ni++)
      O[base + ni * 16 + cl] = (bf16)(oacc[ni][r] * inv);
  }
}

extern "C" void kernel_launch(void* const* d_in, const int* in_sizes, int n_in,
                              void* d_out, int out_size, void* d_ws, size_t ws_size,
                              hipStream_t stream) {
  const void* x     = d_in[0];
  const void* gamma = d_in[1];
  const void* dist  = d_in[2];
  const void* Wqkv  = d_in[3];
  const void* bqkv  = d_in[4];
  const void* Wproj = d_in[5];
  const void* bproj = d_in[6];

  char* ws = (char*)d_ws;
  size_t o = 0;
  int*   flag   = (int*)(ws + o);   o += 16;
  float* gammaf = (float*)(ws + o); o += 32;
  bf16*  xb     = (bf16*)(ws + o);  o += (size_t)M_ * D_ * 2;
  bf16*  distb  = (bf16*)(ws + o);  o += (size_t)N_ * N_ * 2;
  bf16*  bqkvb  = (bf16*)(ws + o);  o += (size_t)D3_ * 2;
  bf16*  bprojb = (bf16*)(ws + o);  o += (size_t)D_ * 2 + 8;
  bf16*  WqkvT  = (bf16*)(ws + o);  o += (size_t)D3_ * D_ * 2;
  bf16*  WprojT = (bf16*)(ws + o);  o += (size_t)D_ * D_ * 2;
  bf16*  Qp     = (bf16*)(ws + o);  o += (size_t)M_ * D_ * 2;
  bf16*  Kp     = (bf16*)(ws + o);  o += (size_t)M_ * D_ * 2;
  bf16*  Vtp    = (bf16*)(ws + o);  o += (size_t)M_ * D_ * 2;
  bf16*  Op     = (bf16*)(ws + o);  o += (size_t)M_ * D_ * 2;
  if (ws_size < o) return;

  detect_small_k<<<1, 256, 0, stream>>>((const unsigned int*)x, bqkv, bproj, gamma,
                                        flag, bqkvb, bprojb, gammaf);
  ingest2_k<<<XBLOCKS + DBLOCKS, 256, 0, stream>>>(x, xb, dist, distb, flag);
  int tilesA = (D3_ / 64) * (D_ / 64);          // 432
  int tilesB = (D_ / 64) * (D_ / 64);           // 144
  ingest_wt_k<<<tilesA + tilesB, 256, 0, stream>>>(Wqkv, WqkvT, Wproj, WprojT,
                                                   flag, tilesA, D3_ / 64);

  // QKV: grid 18 x 64 -> 1D 1152, BYL = 64/8 = 8
  gemm_bt<0, 4, 8><<<18 * 64, 256, 0, stream>>>(
      xb, WqkvT, bqkvb, Qp, Kp, Vtp, nullptr, flag, D_);
  attn_k<<<dim3(B_ * H_ * (N_ / 64)), 256, 0, stream>>>(
      Qp, Kp, Vtp, gammaf, distb, Op);
  // proj: grid 6 x 128 -> 1D 768, BYL = 128/8 = 16
  gemm_bt<1, 2, 16><<<6 * 128, 256, 0, stream>>>(
      Op, WprojT, bprojb, (bf16*)d_out, nullptr, nullptr, (float*)d_out, flag, D_);
}